// Round 3
// baseline (235.074 us; speedup 1.0000x reference)
//
#include <hip/hip_runtime.h>

#define BLOCK 256
#define GRID 2048

__global__ __launch_bounds__(BLOCK) void ratledge_partial(
    const float* __restrict__ yp, const float* __restrict__ yt,
    const float* __restrict__ quants, float* __restrict__ partial, int n)
{
    // Load quant boundaries once (uniform, L1/L2-cached broadcast).
    float q[6];
#pragma unroll
    for (int j = 0; j < 6; ++j) q[j] = quants[j];

    float msum = 0.f;
    float bs[5] = {0.f, 0.f, 0.f, 0.f, 0.f};
    float bc[5] = {0.f, 0.f, 0.f, 0.f, 0.f};

    const int tid    = blockIdx.x * BLOCK + threadIdx.x;
    const int stride = GRID * BLOCK;
    const int n4     = n >> 2;
    const float4* yp4 = (const float4*)yp;
    const float4* yt4 = (const float4*)yt;

    for (int i = tid; i < n4; i += stride) {
        float4 p = yp4[i];
        float4 t = yt4[i];
        float pv[4] = {p.x, p.y, p.z, p.w};
        float tv[4] = {t.x, t.y, t.z, t.w};
#pragma unroll
        for (int e = 0; e < 4; ++e) {
            float v = tv[e];
            float d = pv[e] - v;
            msum = fmaf(d, d, msum);
            // searchsorted(quants, v, side='right') - 1  ==  (#{q_j <= v}) - 1
            int cnt = 0;
#pragma unroll
            for (int j = 0; j < 6; ++j) cnt += (v >= q[j]) ? 1 : 0;
            int idx = (v == q[5]) ? 4 : (cnt - 1);
#pragma unroll
            for (int j = 0; j < 5; ++j) {
                bool m = (idx == j);
                bs[j] += m ? d   : 0.f;
                bc[j] += m ? 1.f : 0.f;
            }
        }
    }
    // scalar tail (n not divisible by 4)
    for (int i = (n4 << 2) + tid; i < n; i += stride) {
        float v = yt[i];
        float d = yp[i] - v;
        msum = fmaf(d, d, msum);
        int cnt = 0;
#pragma unroll
        for (int j = 0; j < 6; ++j) cnt += (v >= q[j]) ? 1 : 0;
        int idx = (v == q[5]) ? 4 : (cnt - 1);
#pragma unroll
        for (int j = 0; j < 5; ++j) {
            bool m = (idx == j);
            bs[j] += m ? d   : 0.f;
            bc[j] += m ? 1.f : 0.f;
        }
    }

    // wave64 shuffle reduce of 11 partials
    float vals[11];
    vals[0] = msum;
#pragma unroll
    for (int j = 0; j < 5; ++j) { vals[1 + j] = bs[j]; vals[6 + j] = bc[j]; }
#pragma unroll
    for (int off = 32; off > 0; off >>= 1) {
#pragma unroll
        for (int j = 0; j < 11; ++j)
            vals[j] += __shfl_down(vals[j], off, 64);
    }

    __shared__ float sred[BLOCK / 64][11];
    const int lane = threadIdx.x & 63;
    const int wid  = threadIdx.x >> 6;
    if (lane == 0) {
#pragma unroll
        for (int j = 0; j < 11; ++j) sred[wid][j] = vals[j];
    }
    __syncthreads();
    if (threadIdx.x == 0) {
#pragma unroll
        for (int j = 0; j < 11; ++j) {
            float s = sred[0][j] + sred[1][j] + sred[2][j] + sred[3][j];
            partial[j * GRID + blockIdx.x] = s;  // SoA: coalesced in finalize
        }
    }
}

__global__ __launch_bounds__(64) void ratledge_final(
    const float* __restrict__ partial, float* __restrict__ out, int n)
{
    const int lane = threadIdx.x;
    double acc[11];
#pragma unroll
    for (int j = 0; j < 11; ++j) {
        double a = 0.0;
        for (int i = lane; i < GRID; i += 64)
            a += (double)partial[j * GRID + i];
        acc[j] = a;
    }
#pragma unroll
    for (int off = 32; off > 0; off >>= 1) {
#pragma unroll
        for (int j = 0; j < 11; ++j)
            acc[j] += __shfl_down(acc[j], off, 64);
    }
    if (lane == 0) {
        double mse = acc[0] / (double)n;
        double maxb2 = 0.0;  // torch starts from tensor(0.0)
#pragma unroll
        for (int j = 0; j < 5; ++j) {
            double cntj = acc[6 + j];
            double bias = acc[1 + j] / fmax(cntj, 1.0);
            double b2   = (cntj > 0.0) ? bias * bias : 0.0;
            maxb2 = fmax(maxb2, b2);
        }
        out[0] = (float)(mse + 5.0 * maxb2);
    }
}

extern "C" void kernel_launch(void* const* d_in, const int* in_sizes, int n_in,
                              void* d_out, int out_size, void* d_ws, size_t ws_size,
                              hipStream_t stream) {
    const float* yp = (const float*)d_in[0];
    const float* yt = (const float*)d_in[1];
    const float* q  = (const float*)d_in[2];
    float* partial  = (float*)d_ws;          // GRID*11*4 = 90112 B
    float* out      = (float*)d_out;
    int n = in_sizes[0];

    ratledge_partial<<<GRID, BLOCK, 0, stream>>>(yp, yt, q, partial, n);
    ratledge_final<<<1, 64, 0, stream>>>(partial, out, n);
}

// Round 4
// 155.062 us; speedup vs baseline: 1.5160x; 1.5160x over previous
//
#include <hip/hip_runtime.h>

#define BLOCK 256
#define GRID 2048
#define FBLOCK 1024

__global__ __launch_bounds__(BLOCK) void ratledge_partial(
    const float* __restrict__ yp, const float* __restrict__ yt,
    const float* __restrict__ quants, float* __restrict__ partial, int n)
{
    // Load quant boundaries once (uniform, L1/L2-cached broadcast).
    float q[6];
#pragma unroll
    for (int j = 0; j < 6; ++j) q[j] = quants[j];

    float msum = 0.f;
    float bs[5] = {0.f, 0.f, 0.f, 0.f, 0.f};
    float bc[5] = {0.f, 0.f, 0.f, 0.f, 0.f};

    const int tid    = blockIdx.x * BLOCK + threadIdx.x;
    const int stride = GRID * BLOCK;
    const int n4     = n >> 2;
    const float4* yp4 = (const float4*)yp;
    const float4* yt4 = (const float4*)yt;

    for (int i = tid; i < n4; i += stride) {
        float4 p = yp4[i];
        float4 t = yt4[i];
        float pv[4] = {p.x, p.y, p.z, p.w};
        float tv[4] = {t.x, t.y, t.z, t.w};
#pragma unroll
        for (int e = 0; e < 4; ++e) {
            float v = tv[e];
            float d = pv[e] - v;
            msum = fmaf(d, d, msum);
            // searchsorted(quants, v, side='right') - 1  ==  (#{q_j <= v}) - 1
            int cnt = 0;
#pragma unroll
            for (int j = 0; j < 6; ++j) cnt += (v >= q[j]) ? 1 : 0;
            int idx = (v == q[5]) ? 4 : (cnt - 1);
#pragma unroll
            for (int j = 0; j < 5; ++j) {
                bool m = (idx == j);
                bs[j] += m ? d   : 0.f;
                bc[j] += m ? 1.f : 0.f;
            }
        }
    }
    // scalar tail (n not divisible by 4)
    for (int i = (n4 << 2) + tid; i < n; i += stride) {
        float v = yt[i];
        float d = yp[i] - v;
        msum = fmaf(d, d, msum);
        int cnt = 0;
#pragma unroll
        for (int j = 0; j < 6; ++j) cnt += (v >= q[j]) ? 1 : 0;
        int idx = (v == q[5]) ? 4 : (cnt - 1);
#pragma unroll
        for (int j = 0; j < 5; ++j) {
            bool m = (idx == j);
            bs[j] += m ? d   : 0.f;
            bc[j] += m ? 1.f : 0.f;
        }
    }

    // wave64 shuffle reduce of 11 partials
    float vals[11];
    vals[0] = msum;
#pragma unroll
    for (int j = 0; j < 5; ++j) { vals[1 + j] = bs[j]; vals[6 + j] = bc[j]; }
#pragma unroll
    for (int off = 32; off > 0; off >>= 1) {
#pragma unroll
        for (int j = 0; j < 11; ++j)
            vals[j] += __shfl_down(vals[j], off, 64);
    }

    __shared__ float sred[BLOCK / 64][11];
    const int lane = threadIdx.x & 63;
    const int wid  = threadIdx.x >> 6;
    if (lane == 0) {
#pragma unroll
        for (int j = 0; j < 11; ++j) sred[wid][j] = vals[j];
    }
    __syncthreads();
    if (threadIdx.x == 0) {
#pragma unroll
        for (int j = 0; j < 11; ++j) {
            float s = sred[0][j] + sred[1][j] + sred[2][j] + sred[3][j];
            partial[j * GRID + blockIdx.x] = s;  // SoA: coalesced in finalize
        }
    }
}

__global__ __launch_bounds__(FBLOCK) void ratledge_final(
    const float* __restrict__ partial, float* __restrict__ out, int n)
{
    const int t    = threadIdx.x;
    const int lane = t & 63;
    const int wid  = t >> 6;   // 0..15

    // Each thread: 2 coalesced loads per bin (GRID=2048, FBLOCK=1024).
    double acc[11];
#pragma unroll
    for (int j = 0; j < 11; ++j) {
        float a0 = partial[j * GRID + t];
        float a1 = partial[j * GRID + t + FBLOCK];
        acc[j] = (double)a0 + (double)a1;
    }

    // wave64 shuffle reduce (f64 → two 32b shuffles each, fine)
#pragma unroll
    for (int off = 32; off > 0; off >>= 1) {
#pragma unroll
        for (int j = 0; j < 11; ++j)
            acc[j] += __shfl_down(acc[j], off, 64);
    }

    __shared__ double sred[FBLOCK / 64][11];
    if (lane == 0) {
#pragma unroll
        for (int j = 0; j < 11; ++j) sred[wid][j] = acc[j];
    }
    __syncthreads();

    if (wid == 0) {
        double v[11];
#pragma unroll
        for (int j = 0; j < 11; ++j)
            v[j] = (lane < FBLOCK / 64) ? sred[lane][j] : 0.0;
#pragma unroll
        for (int off = 8; off > 0; off >>= 1) {
#pragma unroll
            for (int j = 0; j < 11; ++j)
                v[j] += __shfl_down(v[j], off, 64);
        }
        if (lane == 0) {
            double mse = v[0] / (double)n;
            double maxb2 = 0.0;  // torch starts from tensor(0.0)
#pragma unroll
            for (int j = 0; j < 5; ++j) {
                double cntj = v[6 + j];
                double bias = v[1 + j] / fmax(cntj, 1.0);
                double b2   = (cntj > 0.0) ? bias * bias : 0.0;
                maxb2 = fmax(maxb2, b2);
            }
            out[0] = (float)(mse + 5.0 * maxb2);
        }
    }
}

extern "C" void kernel_launch(void* const* d_in, const int* in_sizes, int n_in,
                              void* d_out, int out_size, void* d_ws, size_t ws_size,
                              hipStream_t stream) {
    const float* yp = (const float*)d_in[0];
    const float* yt = (const float*)d_in[1];
    const float* q  = (const float*)d_in[2];
    float* partial  = (float*)d_ws;          // GRID*11*4 = 90112 B
    float* out      = (float*)d_out;
    int n = in_sizes[0];

    ratledge_partial<<<GRID, BLOCK, 0, stream>>>(yp, yt, q, partial, n);
    ratledge_final<<<1, FBLOCK, 0, stream>>>(partial, out, n);
}

// Round 5
// 153.787 us; speedup vs baseline: 1.5286x; 1.0083x over previous
//
#include <hip/hip_runtime.h>
#include <math.h>

#define BLOCK 256
#define GRID 2048
#define FBLOCK 1024

__global__ __launch_bounds__(BLOCK) void ratledge_partial(
    const float* __restrict__ yp, const float* __restrict__ yt,
    const float* __restrict__ quants, float* __restrict__ partial, int n)
{
    // quants: uniform address -> scalar loads
    float q[6];
#pragma unroll
    for (int j = 0; j < 6; ++j) q[j] = quants[j];
    const float q5 = q[5];

    float msum = 0.f;
    // suffix accumulators: ss[j] = sum of d over {q_j <= v <= q5}; sc[j] = count
    float ss[5] = {0.f, 0.f, 0.f, 0.f, 0.f};
    unsigned sc[5] = {0u, 0u, 0u, 0u, 0u};

    const int tid    = blockIdx.x * BLOCK + threadIdx.x;
    const int stride = GRID * BLOCK;
    const int n4     = n >> 2;
    const float4* yp4 = (const float4*)yp;
    const float4* yt4 = (const float4*)yt;

    auto body = [&](float p, float v) {
        float d = p - v;
        msum = fmaf(d, d, msum);
        // invalid-high (v > q5, incl. NaN) -> -inf fails every v>=q_j test.
        // v == q5 passes all 5 tests -> lands in bin 4 via differencing. Exact
        // searchsorted(side='right') semantics, no arithmetic-binning assumptions.
        float vv = (v <= q5) ? v : -INFINITY;
#pragma unroll
        for (int j = 0; j < 5; ++j) {
            bool m = (vv >= q[j]);
            ss[j] += m ? d : 0.f;
            sc[j] += m ? 1u : 0u;
        }
    };

    const int trips = n4 / stride;
    int k = 0;
    for (; k + 4 <= trips; k += 4) {
        float4 P[4], T[4];
#pragma unroll
        for (int r = 0; r < 4; ++r) {
            int i = tid + (k + r) * stride;
            P[r] = yp4[i];
            T[r] = yt4[i];
        }
#pragma unroll
        for (int r = 0; r < 4; ++r) {
            body(P[r].x, T[r].x);
            body(P[r].y, T[r].y);
            body(P[r].z, T[r].z);
            body(P[r].w, T[r].w);
        }
    }
    for (; k < trips; ++k) {
        int i = tid + k * stride;
        float4 p = yp4[i];
        float4 t = yt4[i];
        body(p.x, t.x); body(p.y, t.y); body(p.z, t.z); body(p.w, t.w);
    }
    // remainder float4s (n4 % stride)
    {
        int i = tid + trips * stride;
        if (i < n4) {
            float4 p = yp4[i];
            float4 t = yt4[i];
            body(p.x, t.x); body(p.y, t.y); body(p.z, t.z); body(p.w, t.w);
        }
    }
    // scalar tail (n % 4)
    for (int i = (n4 << 2) + tid; i < n; i += stride)
        body(yp[i], yt[i]);

    // wave64 shuffle reduce of 11 partials
    float vals[11];
    vals[0] = msum;
#pragma unroll
    for (int j = 0; j < 5; ++j) { vals[1 + j] = ss[j]; vals[6 + j] = (float)sc[j]; }
#pragma unroll
    for (int off = 32; off > 0; off >>= 1) {
#pragma unroll
        for (int j = 0; j < 11; ++j)
            vals[j] += __shfl_down(vals[j], off, 64);
    }

    __shared__ float sred[BLOCK / 64][11];
    const int lane = threadIdx.x & 63;
    const int wid  = threadIdx.x >> 6;
    if (lane == 0) {
#pragma unroll
        for (int j = 0; j < 11; ++j) sred[wid][j] = vals[j];
    }
    __syncthreads();
    if (threadIdx.x == 0) {
#pragma unroll
        for (int j = 0; j < 11; ++j) {
            float s = sred[0][j] + sred[1][j] + sred[2][j] + sred[3][j];
            partial[j * GRID + blockIdx.x] = s;  // SoA: coalesced in finalize
        }
    }
}

__global__ __launch_bounds__(FBLOCK) void ratledge_final(
    const float* __restrict__ partial, float* __restrict__ out, int n)
{
    const int t    = threadIdx.x;
    const int lane = t & 63;
    const int wid  = t >> 6;   // 0..15

    // Each thread: 2 coalesced loads per slot (GRID=2048, FBLOCK=1024).
    double acc[11];
#pragma unroll
    for (int j = 0; j < 11; ++j) {
        float a0 = partial[j * GRID + t];
        float a1 = partial[j * GRID + t + FBLOCK];
        acc[j] = (double)a0 + (double)a1;
    }

#pragma unroll
    for (int off = 32; off > 0; off >>= 1) {
#pragma unroll
        for (int j = 0; j < 11; ++j)
            acc[j] += __shfl_down(acc[j], off, 64);
    }

    __shared__ double sred[FBLOCK / 64][11];
    if (lane == 0) {
#pragma unroll
        for (int j = 0; j < 11; ++j) sred[wid][j] = acc[j];
    }
    __syncthreads();

    if (wid == 0) {
        double v[11];
#pragma unroll
        for (int j = 0; j < 11; ++j)
            v[j] = (lane < FBLOCK / 64) ? sred[lane][j] : 0.0;
#pragma unroll
        for (int off = 8; off > 0; off >>= 1) {
#pragma unroll
            for (int j = 0; j < 11; ++j)
                v[j] += __shfl_down(v[j], off, 64);
        }
        if (lane == 0) {
            double mse = v[0] / (double)n;
            double maxb2 = 0.0;  // torch starts from tensor(0.0)
            // un-difference the suffix accumulators: bin j = suffix j - suffix j+1
#pragma unroll
            for (int j = 0; j < 5; ++j) {
                double Sj  = v[1 + j];
                double Sj1 = (j < 4) ? v[2 + j] : 0.0;
                double Cj  = v[6 + j];
                double Cj1 = (j < 4) ? v[7 + j] : 0.0;
                double cnt = Cj - Cj1;
                double sum = Sj - Sj1;
                double bias = sum / fmax(cnt, 1.0);
                double b2   = (cnt > 0.0) ? bias * bias : 0.0;
                maxb2 = fmax(maxb2, b2);
            }
            out[0] = (float)(mse + 5.0 * maxb2);
        }
    }
}

extern "C" void kernel_launch(void* const* d_in, const int* in_sizes, int n_in,
                              void* d_out, int out_size, void* d_ws, size_t ws_size,
                              hipStream_t stream) {
    const float* yp = (const float*)d_in[0];
    const float* yt = (const float*)d_in[1];
    const float* q  = (const float*)d_in[2];
    float* partial  = (float*)d_ws;          // GRID*11*4 = 90112 B
    float* out      = (float*)d_out;
    int n = in_sizes[0];

    ratledge_partial<<<GRID, BLOCK, 0, stream>>>(yp, yt, q, partial, n);
    ratledge_final<<<1, FBLOCK, 0, stream>>>(partial, out, n);
}